// Round 1
// baseline (92.265 us; speedup 1.0000x reference)
//
#include <hip/hip_runtime.h>
#include <math.h>

#define NB 262144
#define MAXC 13

// One thread per (batch, corner). Output y-component is always 0 (all scaled
// corners share y = -1.6*ratio, so edge vectors have vec.y == 0 exactly).
// Cases: j < nums  -> normal of edge (j -> next_idx)
//        j == nums -> normal of edge (0 -> 1)   (reference's wrap row n[:,0])
//        j > nums  -> zeros
__global__ __launch_bounds__(256) void render_normals_kernel(
    const float* __restrict__ gt,          // (NB, MAXC, 2) [lon, lat]
    const int* __restrict__ corner_nums,   // (NB,)
    const float* __restrict__ ratio,       // (NB,)
    float* __restrict__ out)               // (NB, MAXC, 3)
{
    int t = blockIdx.x * blockDim.x + threadIdx.x;
    if (t >= NB * MAXC) return;
    int b = t / MAXC;
    int j = t - b * MAXC;
    int nums = corner_nums[b];

    float ox = 0.0f, oz = 0.0f;
    if (j <= nums) {
        int i0, i1;
        if (j == nums) { i0 = 0; i1 = 1; }
        else           { i0 = j; i1 = (j + 1 == nums) ? 0 : (j + 1); }

        float hs = -1.6f * ratio[b];
        const float2* g2 = (const float2*)gt;
        float2 p0 = g2[b * MAXC + i0];  // (lon, lat)
        float2 p1 = g2[b * MAXC + i1];

        float sl0, cl0, st0, ct0;
        sincosf(p0.x, &sl0, &cl0);
        sincosf(p0.y, &st0, &ct0);
        float k0 = hs * ct0 / st0;          // lat in [-1.4,-0.2]: st0 != 0
        float x0 = k0 * sl0, z0 = k0 * cl0;

        float sl1, cl1, st1, ct1;
        sincosf(p1.x, &sl1, &cl1);
        sincosf(p1.y, &st1, &ct1);
        float k1 = hs * ct1 / st1;
        float x1 = k1 * sl1, z1 = k1 * cl1;

        float dx = x1 - x0;
        float dz = z1 - z0;
        float inv = rsqrtf(dx * dx + dz * dz);
        ox = -dz * inv;
        oz =  dx * inv;
    }

    out[3 * t + 0] = ox;
    out[3 * t + 1] = 0.0f;
    out[3 * t + 2] = oz;
}

extern "C" void kernel_launch(void* const* d_in, const int* in_sizes, int n_in,
                              void* d_out, int out_size, void* d_ws, size_t ws_size,
                              hipStream_t stream) {
    const float* gt     = (const float*)d_in[0];  // GT_up (NB, MAXC, 2) f32
    const int*   nums   = (const int*)d_in[1];    // corner_nums (NB,) i32
    const float* ratio  = (const float*)d_in[2];  // up_down_ratio (NB,) f32
    float* out = (float*)d_out;                   // (NB, MAXC, 3) f32

    int total = NB * MAXC;                        // 3,407,872 = 13312 * 256
    int block = 256;
    int grid = (total + block - 1) / block;
    render_normals_kernel<<<grid, block, 0, stream>>>(gt, nums, ratio, out);
}

// Round 2
// 90.309 us; speedup vs baseline: 1.0217x; 1.0217x over previous
//
#include <hip/hip_runtime.h>
#include <math.h>

#define NB 262144
#define MAXC 13
#define INV_2PI 0.15915494309189535f

// One thread per (batch, corner). Output y-component is always 0 (all scaled
// corners share y = -1.6*ratio, so edge vectors have vec.y == 0 exactly).
// Cases: j < nums  -> normal of edge (j -> next_idx)
//        j == nums -> normal of edge (0 -> 1)   (reference's wrap row n[:,0])
//        j > nums  -> zeros
//
// Uses HW transcendentals (v_sin_f32/v_cos_f32 via __sinf/__cosf): inputs are
// in [-pi, pi], well inside the HW-accurate range; absmax threshold 2e-2
// leaves ~4 orders of magnitude of slack over the ~1e-6 HW error.
__global__ __launch_bounds__(256) void render_normals_kernel(
    const float* __restrict__ gt,          // (NB, MAXC, 2) [lon, lat]
    const int* __restrict__ corner_nums,   // (NB,)
    const float* __restrict__ ratio,       // (NB,)
    float* __restrict__ out)               // (NB, MAXC, 3)
{
    int t = blockIdx.x * blockDim.x + threadIdx.x;
    if (t >= NB * MAXC) return;
    int b = t / MAXC;
    int j = t - b * MAXC;
    int nums = corner_nums[b];

    float ox = 0.0f, oz = 0.0f;
    if (j <= nums) {
        int i0, i1;
        if (j == nums) { i0 = 0; i1 = 1; }
        else           { i0 = j; i1 = (j + 1 == nums) ? 0 : (j + 1); }

        float hs = -1.6f * ratio[b];
        const float2* g2 = (const float2*)gt;
        float2 p0 = g2[b * MAXC + i0];  // (lon, lat)
        float2 p1 = g2[b * MAXC + i1];

        // corner 0: x = k*sin(lon), z = k*cos(lon), k = hs*cot(lat)
        float a0 = p0.x * INV_2PI, t0 = p0.y * INV_2PI;
        float sl0 = __sinf(p0.x), cl0 = __cosf(p0.x);
        float st0 = __sinf(p0.y), ct0 = __cosf(p0.y);
        float k0 = hs * ct0 * __frcp_rn(st0);   // lat in [-1.4,-0.2]: |st0|>=0.198
        float x0 = k0 * sl0, z0 = k0 * cl0;
        (void)a0; (void)t0;

        float sl1 = __sinf(p1.x), cl1 = __cosf(p1.x);
        float st1 = __sinf(p1.y), ct1 = __cosf(p1.y);
        float k1 = hs * ct1 * __frcp_rn(st1);
        float x1 = k1 * sl1, z1 = k1 * cl1;

        float dx = x1 - x0;
        float dz = z1 - z0;
        float inv = __frsqrt_rn(dx * dx + dz * dz);
        ox = -dz * inv;
        oz =  dx * inv;
    }

    out[3 * t + 0] = ox;
    out[3 * t + 1] = 0.0f;
    out[3 * t + 2] = oz;
}

extern "C" void kernel_launch(void* const* d_in, const int* in_sizes, int n_in,
                              void* d_out, int out_size, void* d_ws, size_t ws_size,
                              hipStream_t stream) {
    const float* gt     = (const float*)d_in[0];  // GT_up (NB, MAXC, 2) f32
    const int*   nums   = (const int*)d_in[1];    // corner_nums (NB,) i32
    const float* ratio  = (const float*)d_in[2];  // up_down_ratio (NB,) f32
    float* out = (float*)d_out;                   // (NB, MAXC, 3) f32

    int total = NB * MAXC;                        // 3,407,872 = 13312 * 256
    int block = 256;
    int grid = (total + block - 1) / block;
    render_normals_kernel<<<grid, block, 0, stream>>>(gt, nums, ratio, out);
}